// Round 5
// baseline (234.717 us; speedup 1.0000x reference)
//
#include <hip/hip_runtime.h>
#include <math.h>

#define NC   1000                 // NUM_CLASSES
#define NVEC 250                  // float4 chunks per row (1000/4)
#define WPB  4                    // waves per block (256 threads)
#define NBLK 2048                 // 8 blocks/CU * 256 CUs -> 32 waves/CU resident
#define L2E  1.4426950408889634f  // log2(e)

typedef float v4f __attribute__((ext_vector_type(4)));

#if __has_builtin(__builtin_amdgcn_exp2f)
#define FAST_EXP2(x) __builtin_amdgcn_exp2f(x)   // v_exp_f32
#else
#define FAST_EXP2(x) exp2f(x)
#endif

#if __has_builtin(__builtin_amdgcn_rcpf)
#define FAST_RCP(x) __builtin_amdgcn_rcpf(x)     // v_rcp_f32
#else
#define FAST_RCP(x) (1.0f / (x))
#endif

__global__ __launch_bounds__(256, 8)   // pin <=64 VGPR tier: 8 blocks/CU
void smooth_filter_kernel(const float* __restrict__ in,
                          float* __restrict__ out,
                          int rows) {
    const int lane   = threadIdx.x & 63;
    const int nwaves = gridDim.x * WPB;                       // total waves
    const bool tail  = (lane < (NVEC - 192));                 // lanes 0..57 own chunk 3

    int row = blockIdx.x * WPB + (threadIdx.x >> 6);          // this wave's first row
    if (row >= rows) return;                                  // wave-uniform

    // ---- prologue: prefetch first row (4 coalesced float4 loads in flight) ----
    float4 nv0, nv1, nv2, nv3;
    nv3 = make_float4(0.f, 0.f, 0.f, 0.f);
    {
        const float4* __restrict__ rp = (const float4*)(in + (size_t)row * NC);
        nv0 = rp[lane];
        nv1 = rp[lane + 64];
        nv2 = rp[lane + 128];
        if (tail) nv3 = rp[lane + 192];
    }

    while (true) {
        // ---- rotate prefetch buffer into current ----
        const float4 v0 = nv0, v1 = nv1, v2 = nv2, v3 = nv3;
        const int srow = row;
        row += nwaves;

        // ---- issue next row's loads BEFORE the reduce: latency hides under compute ----
        if (row < rows) {
            const float4* __restrict__ np = (const float4*)(in + (size_t)row * NC);
            nv0 = np[lane];
            nv1 = np[lane + 64];
            nv2 = np[lane + 128];
            if (tail) nv3 = np[lane + 192];
        }

        // ---- per-lane partial sums: sum(r), sum(|r|), sum(|r|^2) ----
        float s_r, s_a, s_a2;
        {
            const float a00 = fabsf(v0.x), a01 = fabsf(v0.y), a02 = fabsf(v0.z), a03 = fabsf(v0.w);
            const float a10 = fabsf(v1.x), a11 = fabsf(v1.y), a12 = fabsf(v1.z), a13 = fabsf(v1.w);
            const float a20 = fabsf(v2.x), a21 = fabsf(v2.y), a22 = fabsf(v2.z), a23 = fabsf(v2.w);
            const float a30 = fabsf(v3.x), a31 = fabsf(v3.y), a32 = fabsf(v3.z), a33 = fabsf(v3.w);
            s_r  = ((v0.x + v0.y) + (v0.z + v0.w)) + ((v1.x + v1.y) + (v1.z + v1.w))
                 + ((v2.x + v2.y) + (v2.z + v2.w)) + ((v3.x + v3.y) + (v3.z + v3.w));
            s_a  = ((a00 + a01) + (a02 + a03)) + ((a10 + a11) + (a12 + a13))
                 + ((a20 + a21) + (a22 + a23)) + ((a30 + a31) + (a32 + a33));
            s_a2 = ((a00*a00 + a01*a01) + (a02*a02 + a03*a03)) + ((a10*a10 + a11*a11) + (a12*a12 + a13*a13))
                 + ((a20*a20 + a21*a21) + (a22*a22 + a23*a23)) + ((a30*a30 + a31*a31) + (a32*a32 + a33*a33));
        }

        // ---- wave-64 butterfly: every lane ends with the row totals ----
        #pragma unroll
        for (int off = 32; off > 0; off >>= 1) {
            s_r  += __shfl_xor(s_r,  off, 64);
            s_a  += __shfl_xor(s_a,  off, 64);
            s_a2 += __shfl_xor(s_a2, off, 64);
        }

        // ---- row statistics (uniform across the wave) ----
        const float mean    = s_a * (1.0f / NC);
        const float var     = (s_a2 - (float)NC * mean * mean) * (1.0f / (NC - 1));
        const float inv_std = rsqrtf(var);

        // sigmoid((a-mean)*inv_std) = rcp(1 + exp2(a*kx + bx))
        const float kx = -inv_std * L2E;
        const float bx =  mean * inv_std * L2E;
        const float c  = 1.0f / (NC - 1);
        const float cS = c * s_r;                 // c * sum(r)
        const float cn = c * (float)NC;           // c * n

        // ---- fused epilogue: out = r + w*(cS - cn*r), w = sigmoid(...) ----
        v4f* __restrict__ op = (v4f*)(out + (size_t)srow * NC);
        {
            v4f o;
            o.x = fmaf(FAST_RCP(1.0f + FAST_EXP2(fmaf(fabsf(v0.x), kx, bx))), fmaf(-cn, v0.x, cS), v0.x);
            o.y = fmaf(FAST_RCP(1.0f + FAST_EXP2(fmaf(fabsf(v0.y), kx, bx))), fmaf(-cn, v0.y, cS), v0.y);
            o.z = fmaf(FAST_RCP(1.0f + FAST_EXP2(fmaf(fabsf(v0.z), kx, bx))), fmaf(-cn, v0.z, cS), v0.z);
            o.w = fmaf(FAST_RCP(1.0f + FAST_EXP2(fmaf(fabsf(v0.w), kx, bx))), fmaf(-cn, v0.w, cS), v0.w);
            __builtin_nontemporal_store(o, &op[lane]);
        }
        {
            v4f o;
            o.x = fmaf(FAST_RCP(1.0f + FAST_EXP2(fmaf(fabsf(v1.x), kx, bx))), fmaf(-cn, v1.x, cS), v1.x);
            o.y = fmaf(FAST_RCP(1.0f + FAST_EXP2(fmaf(fabsf(v1.y), kx, bx))), fmaf(-cn, v1.y, cS), v1.y);
            o.z = fmaf(FAST_RCP(1.0f + FAST_EXP2(fmaf(fabsf(v1.z), kx, bx))), fmaf(-cn, v1.z, cS), v1.z);
            o.w = fmaf(FAST_RCP(1.0f + FAST_EXP2(fmaf(fabsf(v1.w), kx, bx))), fmaf(-cn, v1.w, cS), v1.w);
            __builtin_nontemporal_store(o, &op[lane + 64]);
        }
        {
            v4f o;
            o.x = fmaf(FAST_RCP(1.0f + FAST_EXP2(fmaf(fabsf(v2.x), kx, bx))), fmaf(-cn, v2.x, cS), v2.x);
            o.y = fmaf(FAST_RCP(1.0f + FAST_EXP2(fmaf(fabsf(v2.y), kx, bx))), fmaf(-cn, v2.y, cS), v2.y);
            o.z = fmaf(FAST_RCP(1.0f + FAST_EXP2(fmaf(fabsf(v2.z), kx, bx))), fmaf(-cn, v2.z, cS), v2.z);
            o.w = fmaf(FAST_RCP(1.0f + FAST_EXP2(fmaf(fabsf(v2.w), kx, bx))), fmaf(-cn, v2.w, cS), v2.w);
            __builtin_nontemporal_store(o, &op[lane + 128]);
        }
        if (tail) {
            v4f o;
            o.x = fmaf(FAST_RCP(1.0f + FAST_EXP2(fmaf(fabsf(v3.x), kx, bx))), fmaf(-cn, v3.x, cS), v3.x);
            o.y = fmaf(FAST_RCP(1.0f + FAST_EXP2(fmaf(fabsf(v3.y), kx, bx))), fmaf(-cn, v3.y, cS), v3.y);
            o.z = fmaf(FAST_RCP(1.0f + FAST_EXP2(fmaf(fabsf(v3.z), kx, bx))), fmaf(-cn, v3.z, cS), v3.z);
            o.w = fmaf(FAST_RCP(1.0f + FAST_EXP2(fmaf(fabsf(v3.w), kx, bx))), fmaf(-cn, v3.w, cS), v3.w);
            __builtin_nontemporal_store(o, &op[lane + 192]);
        }

        if (row >= rows) break;
    }
}

extern "C" void kernel_launch(void* const* d_in, const int* in_sizes, int n_in,
                              void* d_out, int out_size, void* d_ws, size_t ws_size,
                              hipStream_t stream) {
    const float* in  = (const float*)d_in[0];
    float*       out = (float*)d_out;
    const int rows   = in_sizes[0] / NC;          // 32768
    const int waves  = NBLK * WPB;                // 8192 waves -> 4 rows/wave
    const int blocks = (rows < waves) ? (rows + WPB - 1) / WPB : NBLK;
    smooth_filter_kernel<<<blocks, 256, 0, stream>>>(in, out, rows);
}

// Round 6
// 229.547 us; speedup vs baseline: 1.0225x; 1.0225x over previous
//
#include <hip/hip_runtime.h>
#include <math.h>

#define NC   1000                 // NUM_CLASSES
#define NVEC 250                  // float4 chunks per row (1000/4)
#define WPB  4                    // waves per block (256 threads)
#define RPW  4                    // consecutive rows per wave (2 pairs, pipelined)
#define L2E  1.4426950408889634f  // log2(e)

typedef float v4f __attribute__((ext_vector_type(4)));

#if __has_builtin(__builtin_amdgcn_exp2f)
#define FAST_EXP2(x) __builtin_amdgcn_exp2f(x)   // v_exp_f32
#else
#define FAST_EXP2(x) exp2f(x)
#endif

#if __has_builtin(__builtin_amdgcn_rcpf)
#define FAST_RCP(x) __builtin_amdgcn_rcpf(x)     // v_rcp_f32
#else
#define FAST_RCP(x) (1.0f / (x))
#endif

struct Row { float4 c0, c1, c2, c3; };

__device__ __forceinline__ Row load_row(const float* __restrict__ in, int row,
                                        int lane, bool tail) {
    const float4* __restrict__ rp = (const float4*)(in + (size_t)row * NC);
    Row r;
    r.c0 = rp[lane];
    r.c1 = rp[lane + 64];
    r.c2 = rp[lane + 128];
    r.c3 = tail ? rp[lane + 192] : make_float4(0.f, 0.f, 0.f, 0.f);
    return r;
}

__device__ __forceinline__ void accum_chunk(const float4& c, float& sr, float& sa, float& sa2) {
    const float a0 = fabsf(c.x), a1 = fabsf(c.y), a2 = fabsf(c.z), a3 = fabsf(c.w);
    sr  += (c.x + c.y) + (c.z + c.w);
    sa  += (a0 + a1) + (a2 + a3);
    sa2 += (a0 * a0 + a1 * a1) + (a2 * a2 + a3 * a3);
}

__device__ __forceinline__ float elem(float x, float kx, float bx, float cn, float cS) {
    return fmaf(FAST_RCP(1.0f + FAST_EXP2(fmaf(fabsf(x), kx, bx))), fmaf(-cn, x, cS), x);
}

__device__ __forceinline__ void do_epilogue(const Row& r, float S, float SA, float SA2,
                                            float* __restrict__ out, int row,
                                            int lane, bool tail) {
    const float mean    = SA * (1.0f / NC);
    const float var     = (SA2 - (float)NC * mean * mean) * (1.0f / (NC - 1));
    const float inv_std = rsqrtf(var);
    const float kx = -inv_std * L2E;
    const float bx =  mean * inv_std * L2E;
    const float c  = 1.0f / (NC - 1);
    const float cS = c * S;
    const float cn = c * (float)NC;

    v4f* __restrict__ op = (v4f*)(out + (size_t)row * NC);
    {
        v4f o;
        o.x = elem(r.c0.x, kx, bx, cn, cS);
        o.y = elem(r.c0.y, kx, bx, cn, cS);
        o.z = elem(r.c0.z, kx, bx, cn, cS);
        o.w = elem(r.c0.w, kx, bx, cn, cS);
        __builtin_nontemporal_store(o, &op[lane]);
    }
    {
        v4f o;
        o.x = elem(r.c1.x, kx, bx, cn, cS);
        o.y = elem(r.c1.y, kx, bx, cn, cS);
        o.z = elem(r.c1.z, kx, bx, cn, cS);
        o.w = elem(r.c1.w, kx, bx, cn, cS);
        __builtin_nontemporal_store(o, &op[lane + 64]);
    }
    {
        v4f o;
        o.x = elem(r.c2.x, kx, bx, cn, cS);
        o.y = elem(r.c2.y, kx, bx, cn, cS);
        o.z = elem(r.c2.z, kx, bx, cn, cS);
        o.w = elem(r.c2.w, kx, bx, cn, cS);
        __builtin_nontemporal_store(o, &op[lane + 128]);
    }
    if (tail) {
        v4f o;
        o.x = elem(r.c3.x, kx, bx, cn, cS);
        o.y = elem(r.c3.y, kx, bx, cn, cS);
        o.z = elem(r.c3.z, kx, bx, cn, cS);
        o.w = elem(r.c3.w, kx, bx, cn, cS);
        __builtin_nontemporal_store(o, &op[lane + 192]);
    }
}

__global__ __launch_bounds__(256, 4)   // ~90 VGPR expected; 4+ waves/SIMD
void smooth_filter_kernel(const float* __restrict__ in,
                          float* __restrict__ out,
                          int rows) {
    const int  lane = threadIdx.x & 63;
    const bool tail = (lane < (NVEC - 192));          // lanes 0..57 own chunk 3
    const int  wid  = blockIdx.x * WPB + (threadIdx.x >> 6);
    const int  row0 = wid * RPW;
    if (row0 >= rows) return;                         // wave-uniform

    const bool h1 = (row0 + 1) < rows;
    const bool h2 = (row0 + 2) < rows;
    const bool h3 = (row0 + 3) < rows;

    // ---- issue ALL 16 loads up front: 16 KB/wave in flight.
    //      Compiler waits vmcnt(12)/(8) for pair A; pair B's 8 loads stay
    //      outstanding under pair A's ~1000-cycle compute+store phase. ----
    Row A0 = load_row(in, row0, lane, tail);
    Row A1, B0, B1;
    if (h1) A1 = load_row(in, row0 + 1, lane, tail); else A1 = A0;
    if (h2) B0 = load_row(in, row0 + 2, lane, tail); else B0 = A0;
    if (h3) B1 = load_row(in, row0 + 3, lane, tail); else B1 = A0;

    // ================= pair A =================
    {
        float xr = 0.f, xa = 0.f, xa2 = 0.f;          // row0
        float yr = 0.f, ya = 0.f, ya2 = 0.f;          // row0+1
        accum_chunk(A0.c0, xr, xa, xa2);
        accum_chunk(A0.c1, xr, xa, xa2);
        accum_chunk(A0.c2, xr, xa, xa2);
        accum_chunk(A0.c3, xr, xa, xa2);
        accum_chunk(A1.c0, yr, ya, ya2);
        accum_chunk(A1.c1, yr, ya, ya2);
        accum_chunk(A1.c2, yr, ya, ya2);
        accum_chunk(A1.c3, yr, ya, ya2);

        // two interleaved butterflies: 6 independent shuffles per step
        #pragma unroll
        for (int off = 32; off > 0; off >>= 1) {
            xr  += __shfl_xor(xr,  off, 64);
            yr  += __shfl_xor(yr,  off, 64);
            xa  += __shfl_xor(xa,  off, 64);
            ya  += __shfl_xor(ya,  off, 64);
            xa2 += __shfl_xor(xa2, off, 64);
            ya2 += __shfl_xor(ya2, off, 64);
        }

        do_epilogue(A0, xr, xa, xa2, out, row0, lane, tail);
        if (h1) do_epilogue(A1, yr, ya, ya2, out, row0 + 1, lane, tail);
    }

    // ================= pair B =================
    {
        float xr = 0.f, xa = 0.f, xa2 = 0.f;          // row0+2
        float yr = 0.f, ya = 0.f, ya2 = 0.f;          // row0+3
        accum_chunk(B0.c0, xr, xa, xa2);
        accum_chunk(B0.c1, xr, xa, xa2);
        accum_chunk(B0.c2, xr, xa, xa2);
        accum_chunk(B0.c3, xr, xa, xa2);
        accum_chunk(B1.c0, yr, ya, ya2);
        accum_chunk(B1.c1, yr, ya, ya2);
        accum_chunk(B1.c2, yr, ya, ya2);
        accum_chunk(B1.c3, yr, ya, ya2);

        #pragma unroll
        for (int off = 32; off > 0; off >>= 1) {
            xr  += __shfl_xor(xr,  off, 64);
            yr  += __shfl_xor(yr,  off, 64);
            xa  += __shfl_xor(xa,  off, 64);
            ya  += __shfl_xor(ya,  off, 64);
            xa2 += __shfl_xor(xa2, off, 64);
            ya2 += __shfl_xor(ya2, off, 64);
        }

        if (h2) do_epilogue(B0, xr, xa, xa2, out, row0 + 2, lane, tail);
        if (h3) do_epilogue(B1, yr, ya, ya2, out, row0 + 3, lane, tail);
    }
}

extern "C" void kernel_launch(void* const* d_in, const int* in_sizes, int n_in,
                              void* d_out, int out_size, void* d_ws, size_t ws_size,
                              hipStream_t stream) {
    const float* in  = (const float*)d_in[0];
    float*       out = (float*)d_out;
    const int rows   = in_sizes[0] / NC;                      // 32768
    const int rpb    = WPB * RPW;                             // 16 rows per block
    const int blocks = (rows + rpb - 1) / rpb;                // 2048
    smooth_filter_kernel<<<blocks, 256, 0, stream>>>(in, out, rows);
}